// Round 20
// baseline (490.330 us; speedup 1.0000x reference)
//
#include <hip/hip_runtime.h>
#include <hip/hip_bf16.h>

typedef __attribute__((ext_vector_type(8))) short bf16x8;
typedef __attribute__((ext_vector_type(4))) float f32x4;
typedef __attribute__((ext_vector_type(4))) unsigned short u16x4;

#define BB 4
#define SS 2048
#define DD 2048
#define HH 16
#define HDD 128
// QK buffer: [B*S][4096] bf16 (Q cols 0..2047, K cols 2048..4095), RoPE pre-applied
// Vt buffer: [B*H][128][2048] bf16 (V transposed: hd-major, s contiguous)
// Masking sentinels: finite so (masked) - (init) never yields exp2(0)=1.
#define MASKV (-30000.0f)
#define MINIT (-15000.0f)

__device__ __forceinline__ unsigned short f2bf(float f) {
  __hip_bfloat16 b = __float2bfloat16(f);
  return *reinterpret_cast<unsigned short*>(&b);
}
__device__ __forceinline__ void gl_lds16(const void* g, void* l) {
  __builtin_amdgcn_global_load_lds((const __attribute__((address_space(1))) unsigned int*)g,
                                   (__attribute__((address_space(3))) unsigned int*)l, 16, 0, 0);
}

// ---------------- fused fp32 -> bf16 conversion (single launch, 5 segments) ----
__global__ __launch_bounds__(256) void convert_all(const float* __restrict__ h,
                                                   const float* __restrict__ Wq,
                                                   const float* __restrict__ Wk,
                                                   const float* __restrict__ Wv,
                                                   const float* __restrict__ Wo,
                                                   __hip_bfloat16* __restrict__ hb,
                                                   __hip_bfloat16* __restrict__ wqkv,
                                                   __hip_bfloat16* __restrict__ wo_b) {
  int blk = blockIdx.x;
  const float* src;
  __hip_bfloat16* dst;
  int base;
  if (blk < 16384)      { src = h;  dst = hb;             base = 0; }
  else if (blk < 20480) { src = Wq; dst = wqkv;           base = 16384; }
  else if (blk < 24576) { src = Wk; dst = wqkv + 4194304; base = 20480; }
  else if (blk < 28672) { src = Wv; dst = wqkv + 8388608; base = 24576; }
  else                  { src = Wo; dst = wo_b;           base = 28672; }
  int i = (blk - base) * 256 + threadIdx.x;
  f32x4 v = ((const f32x4*)src)[i];
  u16x4 o;
  o[0] = f2bf(v[0]); o[1] = f2bf(v[1]); o[2] = f2bf(v[2]); o[3] = f2bf(v[3]);
  ((u16x4*)dst)[i] = o;
}

// ---------------- 256x256 4-wave (128x128/wave) B^T GEMM, single-barrier/tile ----
// Geometry change vs R16 (8 waves x 128x64): 4 waves x 128x128 (2x2 grid) cuts
// per-CU LDS-read traffic 1.5x (sum of wave-tile perimeters 1536->1024 units):
// reads 196KB->131KB/tile. LDS-pipe model: reads 1540 + gl_lds writes 1020 =
// ~2560 cyc/tile ~= MFMA 2480 cyc -> balanced pipes (R16's 3330-cyc LDS pipe
// was the ceiling). acc 8x8xf32x4 = 256 VGPR; launch_bounds(256,1) allows 512.
// Same R16 discipline: one vmcnt(0)+barrier per K-tile, staging spread across
// k-slices (A in slice 0, B in slice 1), waves desync, same XOR swizzle.
// MODE 0: epilogue -> QK buffer with fused RoPE (n<4096) or Vt (transposed).
// MODE 1: epilogue -> float C row-major [M][N].
template <int MODE>
__global__ __launch_bounds__(256, 1) void gemm256(const __hip_bfloat16* __restrict__ A,
                                                  const __hip_bfloat16* __restrict__ Bw,
                                                  __hip_bfloat16* __restrict__ Cbf,
                                                  __hip_bfloat16* __restrict__ Vt,
                                                  float* __restrict__ Cf,
                                                  const float* __restrict__ fc,
                                                  const float* __restrict__ fs,
                                                  const int* __restrict__ posp,
                                                  int M, int N, int K) {
  __shared__ __hip_bfloat16 As[2][256 * 64];  // [buf][row*64+col]  32KB each
  __shared__ __hip_bfloat16 Bs[2][256 * 64];  // 32KB each; total 128KB
  const int tid = threadIdx.x;                 // 256 threads
  const int wid = tid >> 6, lane = tid & 63;
  const int l15 = lane & 15, l4 = lane >> 4;
  const int wm = wid >> 1, wn = wid & 1;       // 2 x 2 wave grid; wave owns 128x128

  const int nbn = N >> 8;
  const int nb = (M >> 8) * nbn;
  const int bid = blockIdx.x;
  const int swz = (bid & 7) * (nb >> 3) + (bid >> 3);  // XCD-contiguous (nb%8==0)
  const int bm = swz / nbn, bn = swz % nbn;

  const int NT = K >> 6;  // K-tiles of 64

// stage the full A (or B) 256x64 tile of K-offset K0G into buffer BUF.
// 2048 chunks of 16B = 256 threads x 8; source col pre-swizzled (gl_lds linear).
#define STAGE_A(BUF, K0G)                                                         \
  {                                                                               \
    _Pragma("unroll") for (int i = 0; i < 8; i++) {                               \
      int c = i * 256 + tid, rr = c >> 3, jj = (c & 7) ^ (rr & 7);                \
      gl_lds16(A + ((long)bm * 256 + rr) * K + (K0G) + jj * 8,                    \
               &As[BUF][0] + c * 8);                                              \
    }                                                                             \
  }
#define STAGE_B(BUF, K0G)                                                         \
  {                                                                               \
    _Pragma("unroll") for (int i = 0; i < 8; i++) {                               \
      int c = i * 256 + tid, rr = c >> 3, jj = (c & 7) ^ (rr & 7);                \
      gl_lds16(Bw + ((long)bn * 256 + rr) * K + (K0G) + jj * 8,                   \
               &Bs[BUF][0] + c * 8);                                              \
    }                                                                             \
  }

  f32x4 acc[8][8] = {};

  // prologue: tiles 0 and 1 fully staged
  STAGE_A(0, 0); STAGE_B(0, 0);
  STAGE_A(1, 64); STAGE_B(1, 64);
  __syncthreads();  // vmcnt(0)+lgkm(0)+barrier

  for (int T = 0; T < NT; ++T) {
    const int cur = T & 1;
    const int nxt = cur ^ 1;
    const bool do_stage = (T >= 1) && (T + 1 < NT);
    const int k0n = (T + 1) << 6;

#pragma unroll
    for (int k2 = 0; k2 < 2; ++k2) {
      bf16x8 af[8], bg[8];
#pragma unroll
      for (int ni = 0; ni < 8; ni++) {
        int r = wn * 128 + ni * 16 + l15;
        int j = (k2 * 4 + l4) ^ (r & 7);
        bg[ni] = *(const bf16x8*)(&Bs[cur][0] + r * 64 + j * 8);
      }
#pragma unroll
      for (int mi = 0; mi < 8; mi++) {
        int r = wm * 128 + mi * 16 + l15;
        int j = (k2 * 4 + l4) ^ (r & 7);
        af[mi] = *(const bf16x8*)(&As[cur][0] + r * 64 + j * 8);
      }
      if (do_stage) {
        if (k2 == 0) { STAGE_A(nxt, k0n); }
        else         { STAGE_B(nxt, k0n); }
      }
      // no barrier: ds_read <-> MFMA free to interleave; waves desync
      __builtin_amdgcn_s_setprio(1);
#pragma unroll
      for (int mi = 0; mi < 8; mi++)
#pragma unroll
        for (int ni = 0; ni < 8; ni++)
          acc[mi][ni] = __builtin_amdgcn_mfma_f32_16x16x32_bf16(af[mi], bg[ni],
                                                                acc[mi][ni], 0, 0, 0);
      __builtin_amdgcn_s_setprio(0);
    }
    // single essential sync point per tile
    asm volatile("s_waitcnt vmcnt(0)" ::: "memory");
    __builtin_amdgcn_s_barrier();
    asm volatile("" ::: "memory");
  }
#undef STAGE_A
#undef STAGE_B

  // ---- epilogue ----
  if (MODE == 0) {
    if (bn * 256 < 4096) {
      const int pos = *posp;
#pragma unroll
      for (int mi = 0; mi < 8; mi++)
#pragma unroll
        for (int ni = 0; ni < 8; ni++) {
          int n = bn * 256 + wn * 128 + ni * 16 + l15;
          int hd = n & 127;
          int ip = hd >> 1;
          bool odd = hd & 1;
#pragma unroll
          for (int r = 0; r < 4; r++) {
            float v = acc[mi][ni][r];
            float p = __shfl_xor(v, 1, 64);
            int m = bm * 256 + wm * 128 + mi * 16 + l4 * 4 + r;
            int s = m & (SS - 1);
            float cv = fc[(long)(pos + s) * 64 + ip];
            float sv = fs[(long)(pos + s) * 64 + ip];
            float out = odd ? (p * sv + v * cv) : (v * cv - p * sv);
            Cbf[(long)m * 4096 + n] = __float2bfloat16(out);
          }
        }
    } else {
#pragma unroll
      for (int mi = 0; mi < 8; mi++)
#pragma unroll
        for (int ni = 0; ni < 8; ni++) {
          int e = bn * 256 + wn * 128 + ni * 16 + l15 - 4096;
          int hh = e >> 7, hd = e & 127;
          int m0 = bm * 256 + wm * 128 + mi * 16 + l4 * 4;
          int b = m0 >> 11, s0 = m0 & (SS - 1);
          u16x4 pk;
#pragma unroll
          for (int r = 0; r < 4; r++) pk[r] = f2bf(acc[mi][ni][r]);
          *(u16x4*)(Vt + (((long)(b * HH + hh) * 128 + hd) * SS + s0)) = pk;
        }
    }
  } else {
#pragma unroll
    for (int mi = 0; mi < 8; mi++)
#pragma unroll
      for (int ni = 0; ni < 8; ni++) {
        int n = bn * 256 + wn * 128 + ni * 16 + l15;
#pragma unroll
        for (int r = 0; r < 4; r++) {
          int m = bm * 256 + wm * 128 + mi * 16 + l4 * 4 + r;
          Cf[(long)m * N + n] = acc[mi][ni][r];
        }
      }
  }
}

// ---------------- causal flash attention (round-14, unchanged) ----------------
__global__ __launch_bounds__(256, 2) void attn_k(const __hip_bfloat16* __restrict__ qk,
                                                 const __hip_bfloat16* __restrict__ vt,
                                                 __hip_bfloat16* __restrict__ aout,
                                                 const int* __restrict__ posp) {
  __shared__ __hip_bfloat16 Ks[64 * 128];
  __shared__ __hip_bfloat16 Vs[128 * 64];
  __shared__ __hip_bfloat16 Ps[4][16 * 64];
  const int pos = *posp;
  const int orig = blockIdx.x;
  const int swz = (orig & 7) * 128 + (orig >> 3);
  const int qp = swz & 15, bh = swz >> 4;
  const int b = bh >> 4, h = bh & 15;
  const int tid = threadIdx.x;
  const int wave = tid >> 6, lane = tid & 63;
  const int l15 = lane & 15, l4 = lane >> 4;

  const long kbase = ((long)b * SS) * 4096 + 2048 + h * 128;
  const long vbase = ((long)bh * 128) * SS;
  const float sc2 = 0.08838834764831845f * 1.4426950408889634f;

  const int s_kr[4] = {(0 * 256 + tid) >> 4, (1 * 256 + tid) >> 4, (2 * 256 + tid) >> 4, (3 * 256 + tid) >> 4};
  const int s_kc = tid & 15;
  const int s_hd[4] = {(0 * 256 + tid) >> 3, (1 * 256 + tid) >> 3, (2 * 256 + tid) >> 3, (3 * 256 + tid) >> 3};
  const int s_vc = tid & 7;

  bf16x8 kreg[4], vreg[4];

#define LOADKV(T)                                                                             \
  {                                                                                           \
    const int kv0_ = (T) * 64;                                                                \
    _Pragma("unroll") for (int i = 0; i < 4; i++) {                                           \
      kreg[i] = *(const bf16x8*)(qk + kbase + (long)(kv0_ + s_kr[i]) * 4096 + s_kc * 8);      \
      vreg[i] = *(const bf16x8*)(vt + vbase + (long)s_hd[i] * SS + kv0_ + s_vc * 8);          \
    }                                                                                         \
  }

#define STAGE()                                                                               \
  {                                                                                           \
    _Pragma("unroll") for (int i = 0; i < 4; i++) {                                           \
      *(bf16x8*)(Ks + ((s_kr[i] * 128 + s_kc * 8) ^ ((s_kr[i] & 7) << 3))) = kreg[i];         \
      *(bf16x8*)(Vs + ((s_hd[i] * 64 + s_vc * 8) ^ ((s_hd[i] & 7) << 3))) = vreg[i];          \
    }                                                                                         \
  }

  for (int half = 0; half < 2; ++half) {
    const int qb = half ? (31 - qp) : qp;
    const int qwb = qb * 64 + wave * 16;

    bf16x8 qf[4];
#pragma unroll
    for (int kk = 0; kk < 4; kk++) {
      long row = (long)b * SS + qwb + l15;
      qf[kk] = *(const bf16x8*)(qk + row * 4096 + h * 128 + kk * 32 + l4 * 8);
    }

    f32x4 accO[8] = {};
    float mrun[4], lrun[4];
#pragma unroll
    for (int r = 0; r < 4; r++) { mrun[r] = MINIT; lrun[r] = 0.f; }

    int ntiles = (pos + qb * 64 + 63) / 64 + 1;
    if (ntiles > SS / 64) ntiles = SS / 64;
#define TT(t) (half ? (ntiles - 1 - (t)) : (t))

    LOADKV(TT(0));
    __syncthreads();
    STAGE();

    for (int t = 0; t < ntiles; ++t) {
      const int kv0 = TT(t) * 64;
      __syncthreads();
      if (t + 1 < ntiles) LOADKV(TT(t + 1));

      f32x4 sfr[4] = {};
      __builtin_amdgcn_s_setprio(1);
#pragma unroll
      for (int ni = 0; ni < 4; ni++) {
        const int key = ni * 16 + l15;
        const int sw = (key & 7) << 3;
#pragma unroll
        for (int kk = 0; kk < 4; kk++) {
          bf16x8 kf = *(const bf16x8*)(Ks + ((key * 128 + kk * 32 + l4 * 8) ^ sw));
          sfr[ni] = __builtin_amdgcn_mfma_f32_16x16x32_bf16(qf[kk], kf, sfr[ni], 0, 0, 0);
        }
      }
      __builtin_amdgcn_s_setprio(0);

      const bool needmask = (kv0 + 63) > (pos + qb * 64);
#pragma unroll
      for (int ni = 0; ni < 4; ni++)
#pragma unroll
        for (int r = 0; r < 4; r++) {
          float v = sfr[ni][r] * sc2;
          if (needmask) {
            int key = kv0 + ni * 16 + l15;
            int q = qwb + l4 * 4 + r;
            if (key > pos + q) v = MASKV;
          }
          sfr[ni][r] = v;
        }

      {
        f32x4 mx = sfr[0];
#pragma unroll
        for (int ni = 1; ni < 4; ni++)
#pragma unroll
          for (int r = 0; r < 4; r++) mx[r] = fmaxf(mx[r], sfr[ni][r]);
#pragma unroll
        for (int d = 1; d < 16; d <<= 1)
#pragma unroll
          for (int r = 0; r < 4; r++) mx[r] = fmaxf(mx[r], __shfl_xor(mx[r], d, 64));

        float growth = mx[0] - mrun[0];
#pragma unroll
        for (int r = 1; r < 4; r++) growth = fmaxf(growth, mx[r] - mrun[r]);
        if (!__all(growth <= 11.0f)) {
          float scal[4];
#pragma unroll
          for (int r = 0; r < 4; r++) {
            float mn = fmaxf(mrun[r], mx[r]);
            scal[r] = exp2f(mrun[r] - mn);
            mrun[r] = mn;
            lrun[r] *= scal[r];   // scal uniform across 16-lane group: valid on partials
          }
#pragma unroll
          for (int ni = 0; ni < 8; ni++)
#pragma unroll
            for (int r = 0; r < 4; r++) accO[ni][r] *= scal[r];
        }

        // per-lane partial sum; cross-lane reduce deferred to epilogue
#pragma unroll
        for (int ni = 0; ni < 4; ni++)
#pragma unroll
          for (int r = 0; r < 4; r++) {
            float p = exp2f(sfr[ni][r] - mrun[r]);
            lrun[r] += p;
            int prow = l4 * 4 + r;
            Ps[wave][(prow * 64 + ni * 16 + l15) ^ ((prow & 7) << 3)] = __float2bfloat16(p);
          }
      }

      __builtin_amdgcn_s_setprio(1);
#pragma unroll
      for (int kk = 0; kk < 2; kk++) {
        int prow = l15;
        bf16x8 pf = *(const bf16x8*)(Ps[wave] + ((prow * 64 + kk * 32 + l4 * 8) ^ ((prow & 7) << 3)));
#pragma unroll
        for (int ni = 0; ni < 8; ni++) {
          int hd = ni * 16 + l15;
          bf16x8 vf = *(const bf16x8*)(Vs + ((hd * 64 + kk * 32 + l4 * 8) ^ ((hd & 7) << 3)));
          accO[ni] = __builtin_amdgcn_mfma_f32_16x16x32_bf16(pf, vf, accO[ni], 0, 0, 0);
        }
      }
      __builtin_amdgcn_s_setprio(0);

      __syncthreads();
      if (t + 1 < ntiles) STAGE();
    }
#undef TT

    // deferred cross-lane lrun reduce (once per q-half)
#pragma unroll
    for (int d = 1; d < 16; d <<= 1)
#pragma unroll
      for (int r = 0; r < 4; r++) lrun[r] += __shfl_xor(lrun[r], d, 64);

    __hip_bfloat16* E = Ks + wave * 2048;
    {
      float inv[4];
#pragma unroll
      for (int r = 0; r < 4; r++) inv[r] = 1.0f / lrun[r];
#pragma unroll
      for (int ni = 0; ni < 8; ni++)
#pragma unroll
        for (int r = 0; r < 4; r++) {
          int row = l4 * 4 + r;
          E[(row * 128 + ni * 16 + l15) ^ ((row & 7) << 3)] =
              __float2bfloat16(accO[ni][r] * inv[r]);
        }
    }
    const long gb = ((long)b * SS + qwb) * 2048 + h * 128;
#pragma unroll
    for (int j = 0; j < 4; j++) {
      int row = j * 4 + l4;
      int c8 = l15 * 8;
      bf16x8 v = *(const bf16x8*)(E + ((row * 128 + c8) ^ ((row & 7) << 3)));
      *(bf16x8*)(aout + gb + (long)row * 2048 + c8) = v;
    }
  }
#undef LOADKV
#undef STAGE
}

extern "C" void kernel_launch(void* const* d_in, const int* in_sizes, int n_in,
                              void* d_out, int out_size, void* d_ws, size_t ws_size,
                              hipStream_t stream) {
  (void)in_sizes; (void)n_in; (void)out_size; (void)ws_size;
  const float* h  = (const float*)d_in[0];
  const float* Wq = (const float*)d_in[1];
  const float* Wk = (const float*)d_in[2];
  const float* Wv = (const float*)d_in[3];
  const float* Wo = (const float*)d_in[4];
  const float* fc = (const float*)d_in[7];
  const float* fs = (const float*)d_in[8];
  const int* pos  = (const int*)d_in[9];
  float* out = (float*)d_out;

  char* ws = (char*)d_ws;
  __hip_bfloat16* hb    = (__hip_bfloat16*)(ws);                 // 33,554,432 B
  __hip_bfloat16* wqkv  = (__hip_bfloat16*)(ws + 33554432);      // 25,165,824 B
  __hip_bfloat16* wo_b  = (__hip_bfloat16*)(ws + 58720256);      //  8,388,608 B
  __hip_bfloat16* qkbuf = (__hip_bfloat16*)(ws + 67108864);      // 67,108,864 B
  __hip_bfloat16* vt    = (__hip_bfloat16*)(ws + 134217728);     // 33,554,432 B
  __hip_bfloat16* aout  = hb;  // alias: hb dead after GEMM1

  // fused fp32 -> bf16 (h + Wq + Wk + Wv + Wo), single launch
  convert_all<<<32768, 256, 0, stream>>>(h, Wq, Wk, Wv, Wo, hb, wqkv, wo_b);

  // QKV projection + fused RoPE: M=8192, N=6144, K=2048  (32x24=768 blocks)
  gemm256<0><<<768, 256, 0, stream>>>(hb, wqkv, qkbuf, vt, nullptr, fc, fs, pos,
                                      8192, 6144, 2048);

  // causal flash attention (balanced, two-stream L2-local, 1024 blocks x 256 threads)
  attn_k<<<1024, 256, 0, stream>>>(qkbuf, vt, aout, pos);

  // output projection: M=8192, N=2048, K=2048 -> fp32 d_out  (32x8=256 blocks)
  gemm256<1><<<256, 256, 0, stream>>>(aout, wo_b, nullptr, nullptr, out, nullptr,
                                      nullptr, nullptr, 8192, 2048, 2048);
}

// Round 21
// 457.965 us; speedup vs baseline: 1.0707x; 1.0707x over previous
//
#include <hip/hip_runtime.h>
#include <hip/hip_bf16.h>

typedef __attribute__((ext_vector_type(8))) short bf16x8;
typedef __attribute__((ext_vector_type(4))) float f32x4;
typedef __attribute__((ext_vector_type(4))) unsigned short u16x4;

#define BB 4
#define SS 2048
#define DD 2048
#define HH 16
#define HDD 128
// QK buffer: [B*S][4096] bf16 (Q cols 0..2047, K cols 2048..4095), RoPE pre-applied
// Vt buffer: [B*H][128][2048] bf16 (V transposed: hd-major, s contiguous)
// Masking sentinels: finite so (masked) - (init) never yields exp2(0)=1.
#define MASKV (-30000.0f)
#define MINIT (-15000.0f)

__device__ __forceinline__ unsigned short f2bf(float f) {
  __hip_bfloat16 b = __float2bfloat16(f);
  return *reinterpret_cast<unsigned short*>(&b);
}
__device__ __forceinline__ void gl_lds16(const void* g, void* l) {
  __builtin_amdgcn_global_load_lds((const __attribute__((address_space(1))) unsigned int*)g,
                                   (__attribute__((address_space(3))) unsigned int*)l, 16, 0, 0);
}

// ---------------- fused fp32 -> bf16 conversion (single launch, 5 segments) ----
__global__ __launch_bounds__(256) void convert_all(const float* __restrict__ h,
                                                   const float* __restrict__ Wq,
                                                   const float* __restrict__ Wk,
                                                   const float* __restrict__ Wv,
                                                   const float* __restrict__ Wo,
                                                   __hip_bfloat16* __restrict__ hb,
                                                   __hip_bfloat16* __restrict__ wqkv,
                                                   __hip_bfloat16* __restrict__ wo_b) {
  int blk = blockIdx.x;
  const float* src;
  __hip_bfloat16* dst;
  int base;
  if (blk < 16384)      { src = h;  dst = hb;             base = 0; }
  else if (blk < 20480) { src = Wq; dst = wqkv;           base = 16384; }
  else if (blk < 24576) { src = Wk; dst = wqkv + 4194304; base = 20480; }
  else if (blk < 28672) { src = Wv; dst = wqkv + 8388608; base = 24576; }
  else                  { src = Wo; dst = wo_b;           base = 28672; }
  int i = (blk - base) * 256 + threadIdx.x;
  f32x4 v = ((const f32x4*)src)[i];
  u16x4 o;
  o[0] = f2bf(v[0]); o[1] = f2bf(v[1]); o[2] = f2bf(v[2]); o[3] = f2bf(v[3]);
  ((u16x4*)dst)[i] = o;
}

// ---------------- 256x256 8-wave B^T GEMM, single-barrier-per-tile (R16 EXACT) ---
// Best-measured of 8 structural variants: 206 us MODE-0, MfmaUtil 45.4%,
// 0 bank conflicts, reproduced twice. One barrier per K-tile; waves desync;
// ds_read/MFMA interleave in one basic block; staging SPREAD across k-slices
// (tile-top burst contends with ds_reads on the LDS pipe: R11 263, R17 242);
// 8 waves x 128x64 keeps 2 waves/SIMD of TLP (4-wave 128x128 variant: 250us,
// occupancy 10.7% — latency exposure beats the 1.5x LDS-traffic cut).
// MODE 0: epilogue -> QK buffer with fused RoPE (n<4096) or Vt (transposed).
// MODE 1: epilogue -> float C row-major [M][N].
template <int MODE>
__global__ __launch_bounds__(512, 1) void gemm256(const __hip_bfloat16* __restrict__ A,
                                                  const __hip_bfloat16* __restrict__ Bw,
                                                  __hip_bfloat16* __restrict__ Cbf,
                                                  __hip_bfloat16* __restrict__ Vt,
                                                  float* __restrict__ Cf,
                                                  const float* __restrict__ fc,
                                                  const float* __restrict__ fs,
                                                  const int* __restrict__ posp,
                                                  int M, int N, int K) {
  __shared__ __hip_bfloat16 As[2][2][128 * 64];  // [buf][half][row*64+col]  64KB
  __shared__ __hip_bfloat16 Bs[2][2][128 * 64];  // 64KB
  const int tid = threadIdx.x;
  const int wid = tid >> 6, lane = tid & 63;
  const int l15 = lane & 15, l4 = lane >> 4;
  const int wm = wid >> 2, wn = wid & 3;  // 2 x 4 wave grid; wave owns 128x64

  const int nbn = N >> 8;
  const int nb = (M >> 8) * nbn;
  const int bid = blockIdx.x;
  const int swz = (bid & 7) * (nb >> 3) + (bid >> 3);  // XCD-contiguous (nb%8==0)
  const int bm = swz / nbn, bn = swz % nbn;

  const int NT = K >> 6;  // K-tiles of 64

#define STAGE_HALF(Q, BUF, K0G)                                                   \
  {                                                                               \
    if ((Q) < 2) {                                                                \
      const long rowb = (long)bm * 256 + (Q) * 128;                               \
      _Pragma("unroll") for (int i = 0; i < 2; i++) {                             \
        int c = i * 512 + tid, rr = c >> 3, jj = (c & 7) ^ (rr & 7);              \
        gl_lds16(A + (rowb + rr) * (long)K + (K0G) + jj * 8,                      \
                 &As[BUF][(Q)][0] + c * 8);                                       \
      }                                                                           \
    } else {                                                                      \
      const long rowb = (long)bn * 256 + ((Q) - 2) * 128;                         \
      _Pragma("unroll") for (int i = 0; i < 2; i++) {                             \
        int c = i * 512 + tid, rr = c >> 3, jj = (c & 7) ^ (rr & 7);              \
        gl_lds16(Bw + (rowb + rr) * (long)K + (K0G) + jj * 8,                     \
                 &Bs[BUF][(Q) - 2][0] + c * 8);                                   \
      }                                                                           \
    }                                                                             \
  }

  f32x4 acc[8][4] = {};

  // prologue: tiles 0 and 1 fully staged
#pragma unroll
  for (int q = 0; q < 4; ++q) STAGE_HALF(q, 0, 0);
#pragma unroll
  for (int q = 0; q < 4; ++q) STAGE_HALF(q, 1, 64);
  __syncthreads();  // vmcnt(0)+lgkm(0)+barrier

  for (int T = 0; T < NT; ++T) {
    const int cur = T & 1;
    const int nxt = cur ^ 1;
    const bool do_stage = (T >= 1) && (T + 1 < NT);
    const int k0n = (T + 1) << 6;

#pragma unroll
    for (int k2 = 0; k2 < 2; ++k2) {
      bf16x8 af[8], bg[4];
#pragma unroll
      for (int ni = 0; ni < 4; ni++) {
        int r = (wn & 1) * 64 + ni * 16 + l15;
        int j = (k2 * 4 + l4) ^ (r & 7);
        bg[ni] = *(const bf16x8*)(&Bs[cur][wn >> 1][0] + r * 64 + j * 8);
      }
#pragma unroll
      for (int mi = 0; mi < 8; mi++) {
        int r = mi * 16 + l15;
        int j = (k2 * 4 + l4) ^ (r & 7);
        af[mi] = *(const bf16x8*)(&As[cur][wm][0] + r * 64 + j * 8);
      }
      if (do_stage) {
        if (k2 == 0) { STAGE_HALF(0, nxt, k0n); STAGE_HALF(1, nxt, k0n); }
        else         { STAGE_HALF(2, nxt, k0n); STAGE_HALF(3, nxt, k0n); }
      }
      // no barrier: ds_read <-> MFMA free to interleave; waves desync
      __builtin_amdgcn_s_setprio(1);
#pragma unroll
      for (int mi = 0; mi < 8; mi++)
#pragma unroll
        for (int ni = 0; ni < 4; ni++)
          acc[mi][ni] = __builtin_amdgcn_mfma_f32_16x16x32_bf16(af[mi], bg[ni],
                                                                acc[mi][ni], 0, 0, 0);
      __builtin_amdgcn_s_setprio(0);
    }
    // single essential sync point per tile
    asm volatile("s_waitcnt vmcnt(0)" ::: "memory");
    __builtin_amdgcn_s_barrier();
    asm volatile("" ::: "memory");
  }
#undef STAGE_HALF

  // ---- epilogue ----
  if (MODE == 0) {
    if (bn * 256 < 4096) {
      const int pos = *posp;
#pragma unroll
      for (int mi = 0; mi < 8; mi++)
#pragma unroll
        for (int ni = 0; ni < 4; ni++) {
          int n = bn * 256 + wn * 64 + ni * 16 + l15;
          int hd = n & 127;
          int ip = hd >> 1;
          bool odd = hd & 1;
#pragma unroll
          for (int r = 0; r < 4; r++) {
            float v = acc[mi][ni][r];
            float p = __shfl_xor(v, 1, 64);
            int m = bm * 256 + wm * 128 + mi * 16 + l4 * 4 + r;
            int s = m & (SS - 1);
            float cv = fc[(long)(pos + s) * 64 + ip];
            float sv = fs[(long)(pos + s) * 64 + ip];
            float out = odd ? (p * sv + v * cv) : (v * cv - p * sv);
            Cbf[(long)m * 4096 + n] = __float2bfloat16(out);
          }
        }
    } else {
#pragma unroll
      for (int mi = 0; mi < 8; mi++)
#pragma unroll
        for (int ni = 0; ni < 4; ni++) {
          int e = bn * 256 + wn * 64 + ni * 16 + l15 - 4096;
          int hh = e >> 7, hd = e & 127;
          int m0 = bm * 256 + wm * 128 + mi * 16 + l4 * 4;
          int b = m0 >> 11, s0 = m0 & (SS - 1);
          u16x4 pk;
#pragma unroll
          for (int r = 0; r < 4; r++) pk[r] = f2bf(acc[mi][ni][r]);
          *(u16x4*)(Vt + (((long)(b * HH + hh) * 128 + hd) * SS + s0)) = pk;
        }
    }
  } else {
#pragma unroll
    for (int mi = 0; mi < 8; mi++)
#pragma unroll
      for (int ni = 0; ni < 4; ni++) {
        int n = bn * 256 + wn * 64 + ni * 16 + l15;
#pragma unroll
        for (int r = 0; r < 4; r++) {
          int m = bm * 256 + wm * 128 + mi * 16 + l4 * 4 + r;
          Cf[(long)m * N + n] = acc[mi][ni][r];
        }
      }
  }
}

// ---------------- causal flash attention (round-14, unchanged) ----------------
__global__ __launch_bounds__(256, 2) void attn_k(const __hip_bfloat16* __restrict__ qk,
                                                 const __hip_bfloat16* __restrict__ vt,
                                                 __hip_bfloat16* __restrict__ aout,
                                                 const int* __restrict__ posp) {
  __shared__ __hip_bfloat16 Ks[64 * 128];
  __shared__ __hip_bfloat16 Vs[128 * 64];
  __shared__ __hip_bfloat16 Ps[4][16 * 64];
  const int pos = *posp;
  const int orig = blockIdx.x;
  const int swz = (orig & 7) * 128 + (orig >> 3);
  const int qp = swz & 15, bh = swz >> 4;
  const int b = bh >> 4, h = bh & 15;
  const int tid = threadIdx.x;
  const int wave = tid >> 6, lane = tid & 63;
  const int l15 = lane & 15, l4 = lane >> 4;

  const long kbase = ((long)b * SS) * 4096 + 2048 + h * 128;
  const long vbase = ((long)bh * 128) * SS;
  const float sc2 = 0.08838834764831845f * 1.4426950408889634f;

  const int s_kr[4] = {(0 * 256 + tid) >> 4, (1 * 256 + tid) >> 4, (2 * 256 + tid) >> 4, (3 * 256 + tid) >> 4};
  const int s_kc = tid & 15;
  const int s_hd[4] = {(0 * 256 + tid) >> 3, (1 * 256 + tid) >> 3, (2 * 256 + tid) >> 3, (3 * 256 + tid) >> 3};
  const int s_vc = tid & 7;

  bf16x8 kreg[4], vreg[4];

#define LOADKV(T)                                                                             \
  {                                                                                           \
    const int kv0_ = (T) * 64;                                                                \
    _Pragma("unroll") for (int i = 0; i < 4; i++) {                                           \
      kreg[i] = *(const bf16x8*)(qk + kbase + (long)(kv0_ + s_kr[i]) * 4096 + s_kc * 8);      \
      vreg[i] = *(const bf16x8*)(vt + vbase + (long)s_hd[i] * SS + kv0_ + s_vc * 8);          \
    }                                                                                         \
  }

#define STAGE()                                                                               \
  {                                                                                           \
    _Pragma("unroll") for (int i = 0; i < 4; i++) {                                           \
      *(bf16x8*)(Ks + ((s_kr[i] * 128 + s_kc * 8) ^ ((s_kr[i] & 7) << 3))) = kreg[i];         \
      *(bf16x8*)(Vs + ((s_hd[i] * 64 + s_vc * 8) ^ ((s_hd[i] & 7) << 3))) = vreg[i];          \
    }                                                                                         \
  }

  for (int half = 0; half < 2; ++half) {
    const int qb = half ? (31 - qp) : qp;
    const int qwb = qb * 64 + wave * 16;

    bf16x8 qf[4];
#pragma unroll
    for (int kk = 0; kk < 4; kk++) {
      long row = (long)b * SS + qwb + l15;
      qf[kk] = *(const bf16x8*)(qk + row * 4096 + h * 128 + kk * 32 + l4 * 8);
    }

    f32x4 accO[8] = {};
    float mrun[4], lrun[4];
#pragma unroll
    for (int r = 0; r < 4; r++) { mrun[r] = MINIT; lrun[r] = 0.f; }

    int ntiles = (pos + qb * 64 + 63) / 64 + 1;
    if (ntiles > SS / 64) ntiles = SS / 64;
#define TT(t) (half ? (ntiles - 1 - (t)) : (t))

    LOADKV(TT(0));
    __syncthreads();
    STAGE();

    for (int t = 0; t < ntiles; ++t) {
      const int kv0 = TT(t) * 64;
      __syncthreads();
      if (t + 1 < ntiles) LOADKV(TT(t + 1));

      f32x4 sfr[4] = {};
      __builtin_amdgcn_s_setprio(1);
#pragma unroll
      for (int ni = 0; ni < 4; ni++) {
        const int key = ni * 16 + l15;
        const int sw = (key & 7) << 3;
#pragma unroll
        for (int kk = 0; kk < 4; kk++) {
          bf16x8 kf = *(const bf16x8*)(Ks + ((key * 128 + kk * 32 + l4 * 8) ^ sw));
          sfr[ni] = __builtin_amdgcn_mfma_f32_16x16x32_bf16(qf[kk], kf, sfr[ni], 0, 0, 0);
        }
      }
      __builtin_amdgcn_s_setprio(0);

      const bool needmask = (kv0 + 63) > (pos + qb * 64);
#pragma unroll
      for (int ni = 0; ni < 4; ni++)
#pragma unroll
        for (int r = 0; r < 4; r++) {
          float v = sfr[ni][r] * sc2;
          if (needmask) {
            int key = kv0 + ni * 16 + l15;
            int q = qwb + l4 * 4 + r;
            if (key > pos + q) v = MASKV;
          }
          sfr[ni][r] = v;
        }

      {
        f32x4 mx = sfr[0];
#pragma unroll
        for (int ni = 1; ni < 4; ni++)
#pragma unroll
          for (int r = 0; r < 4; r++) mx[r] = fmaxf(mx[r], sfr[ni][r]);
#pragma unroll
        for (int d = 1; d < 16; d <<= 1)
#pragma unroll
          for (int r = 0; r < 4; r++) mx[r] = fmaxf(mx[r], __shfl_xor(mx[r], d, 64));

        float growth = mx[0] - mrun[0];
#pragma unroll
        for (int r = 1; r < 4; r++) growth = fmaxf(growth, mx[r] - mrun[r]);
        if (!__all(growth <= 11.0f)) {
          float scal[4];
#pragma unroll
          for (int r = 0; r < 4; r++) {
            float mn = fmaxf(mrun[r], mx[r]);
            scal[r] = exp2f(mrun[r] - mn);
            mrun[r] = mn;
            lrun[r] *= scal[r];   // scal uniform across 16-lane group: valid on partials
          }
#pragma unroll
          for (int ni = 0; ni < 8; ni++)
#pragma unroll
            for (int r = 0; r < 4; r++) accO[ni][r] *= scal[r];
        }

        // per-lane partial sum; cross-lane reduce deferred to epilogue
#pragma unroll
        for (int ni = 0; ni < 4; ni++)
#pragma unroll
          for (int r = 0; r < 4; r++) {
            float p = exp2f(sfr[ni][r] - mrun[r]);
            lrun[r] += p;
            int prow = l4 * 4 + r;
            Ps[wave][(prow * 64 + ni * 16 + l15) ^ ((prow & 7) << 3)] = __float2bfloat16(p);
          }
      }

      __builtin_amdgcn_s_setprio(1);
#pragma unroll
      for (int kk = 0; kk < 2; kk++) {
        int prow = l15;
        bf16x8 pf = *(const bf16x8*)(Ps[wave] + ((prow * 64 + kk * 32 + l4 * 8) ^ ((prow & 7) << 3)));
#pragma unroll
        for (int ni = 0; ni < 8; ni++) {
          int hd = ni * 16 + l15;
          bf16x8 vf = *(const bf16x8*)(Vs + ((hd * 64 + kk * 32 + l4 * 8) ^ ((hd & 7) << 3)));
          accO[ni] = __builtin_amdgcn_mfma_f32_16x16x32_bf16(pf, vf, accO[ni], 0, 0, 0);
        }
      }
      __builtin_amdgcn_s_setprio(0);

      __syncthreads();
      if (t + 1 < ntiles) STAGE();
    }
#undef TT

    // deferred cross-lane lrun reduce (once per q-half)
#pragma unroll
    for (int d = 1; d < 16; d <<= 1)
#pragma unroll
      for (int r = 0; r < 4; r++) lrun[r] += __shfl_xor(lrun[r], d, 64);

    __hip_bfloat16* E = Ks + wave * 2048;
    {
      float inv[4];
#pragma unroll
      for (int r = 0; r < 4; r++) inv[r] = 1.0f / lrun[r];
#pragma unroll
      for (int ni = 0; ni < 8; ni++)
#pragma unroll
        for (int r = 0; r < 4; r++) {
          int row = l4 * 4 + r;
          E[(row * 128 + ni * 16 + l15) ^ ((row & 7) << 3)] =
              __float2bfloat16(accO[ni][r] * inv[r]);
        }
    }
    const long gb = ((long)b * SS + qwb) * 2048 + h * 128;
#pragma unroll
    for (int j = 0; j < 4; j++) {
      int row = j * 4 + l4;
      int c8 = l15 * 8;
      bf16x8 v = *(const bf16x8*)(E + ((row * 128 + c8) ^ ((row & 7) << 3)));
      *(bf16x8*)(aout + gb + (long)row * 2048 + c8) = v;
    }
  }
#undef LOADKV
#undef STAGE
}

extern "C" void kernel_launch(void* const* d_in, const int* in_sizes, int n_in,
                              void* d_out, int out_size, void* d_ws, size_t ws_size,
                              hipStream_t stream) {
  (void)in_sizes; (void)n_in; (void)out_size; (void)ws_size;
  const float* h  = (const float*)d_in[0];
  const float* Wq = (const float*)d_in[1];
  const float* Wk = (const float*)d_in[2];
  const float* Wv = (const float*)d_in[3];
  const float* Wo = (const float*)d_in[4];
  const float* fc = (const float*)d_in[7];
  const float* fs = (const float*)d_in[8];
  const int* pos  = (const int*)d_in[9];
  float* out = (float*)d_out;

  char* ws = (char*)d_ws;
  __hip_bfloat16* hb    = (__hip_bfloat16*)(ws);                 // 33,554,432 B
  __hip_bfloat16* wqkv  = (__hip_bfloat16*)(ws + 33554432);      // 25,165,824 B
  __hip_bfloat16* wo_b  = (__hip_bfloat16*)(ws + 58720256);      //  8,388,608 B
  __hip_bfloat16* qkbuf = (__hip_bfloat16*)(ws + 67108864);      // 67,108,864 B
  __hip_bfloat16* vt    = (__hip_bfloat16*)(ws + 134217728);     // 33,554,432 B
  __hip_bfloat16* aout  = hb;  // alias: hb dead after GEMM1

  // fused fp32 -> bf16 (h + Wq + Wk + Wv + Wo), single launch
  convert_all<<<32768, 256, 0, stream>>>(h, Wq, Wk, Wv, Wo, hb, wqkv, wo_b);

  // QKV projection + fused RoPE: M=8192, N=6144, K=2048  (32x24=768 blocks)
  gemm256<0><<<768, 512, 0, stream>>>(hb, wqkv, qkbuf, vt, nullptr, fc, fs, pos,
                                      8192, 6144, 2048);

  // causal flash attention (balanced, two-stream L2-local, 1024 blocks x 256 threads)
  attn_k<<<1024, 256, 0, stream>>>(qkbuf, vt, aout, pos);

  // output projection: M=8192, N=2048, K=2048 -> fp32 d_out  (32x8=256 blocks)
  gemm256<1><<<256, 512, 0, stream>>>(aout, wo_b, nullptr, nullptr, out, nullptr,
                                      nullptr, nullptr, 8192, 2048, 2048);
}

// Round 22
// 457.125 us; speedup vs baseline: 1.0726x; 1.0018x over previous
//
#include <hip/hip_runtime.h>
#include <hip/hip_bf16.h>

typedef __attribute__((ext_vector_type(8))) short bf16x8;
typedef __attribute__((ext_vector_type(4))) float f32x4;
typedef __attribute__((ext_vector_type(4))) unsigned short u16x4;

#define BB 4
#define SS 2048
#define DD 2048
#define HH 16
#define HDD 128
// QK buffer: [B*S][4096] bf16 (Q cols 0..2047, K cols 2048..4095), RoPE pre-applied
// Vt buffer: [B*H][128][2048] bf16 (V transposed: hd-major, s contiguous)
// Masking sentinels: finite so (masked) - (init) never yields exp2(0)=1.
#define MASKV (-30000.0f)
#define MINIT (-15000.0f)

__device__ __forceinline__ unsigned short f2bf(float f) {
  __hip_bfloat16 b = __float2bfloat16(f);
  return *reinterpret_cast<unsigned short*>(&b);
}
__device__ __forceinline__ void gl_lds16(const void* g, void* l) {
  __builtin_amdgcn_global_load_lds((const __attribute__((address_space(1))) unsigned int*)g,
                                   (__attribute__((address_space(3))) unsigned int*)l, 16, 0, 0);
}

// ---------------- fused fp32 -> bf16 conversion (single launch, 5 segments) ----
__global__ __launch_bounds__(256) void convert_all(const float* __restrict__ h,
                                                   const float* __restrict__ Wq,
                                                   const float* __restrict__ Wk,
                                                   const float* __restrict__ Wv,
                                                   const float* __restrict__ Wo,
                                                   __hip_bfloat16* __restrict__ hb,
                                                   __hip_bfloat16* __restrict__ wqkv,
                                                   __hip_bfloat16* __restrict__ wo_b) {
  int blk = blockIdx.x;
  const float* src;
  __hip_bfloat16* dst;
  int base;
  if (blk < 16384)      { src = h;  dst = hb;             base = 0; }
  else if (blk < 20480) { src = Wq; dst = wqkv;           base = 16384; }
  else if (blk < 24576) { src = Wk; dst = wqkv + 4194304; base = 20480; }
  else if (blk < 28672) { src = Wv; dst = wqkv + 8388608; base = 24576; }
  else                  { src = Wo; dst = wo_b;           base = 28672; }
  int i = (blk - base) * 256 + threadIdx.x;
  f32x4 v = ((const f32x4*)src)[i];
  u16x4 o;
  o[0] = f2bf(v[0]); o[1] = f2bf(v[1]); o[2] = f2bf(v[2]); o[3] = f2bf(v[3]);
  ((u16x4*)dst)[i] = o;
}

// ---------------- 256x256 8-wave B^T GEMM, single-barrier-per-tile ----------------
// R16 structure, MINUS s_setprio around MFMA (m190: setprio on GEMM is
// null-to-negative; the desync structure needs reader-waves to win issue
// arbitration while MFMA-waves crunch — setprio(1) biases against that).
// One barrier per K-tile; waves desync; ds_read/MFMA interleave; staging
// spread across k-slices. 206us/45.4% with setprio (reproduced 3x).
// MODE 0: epilogue -> QK buffer with fused RoPE (n<4096) or Vt (transposed).
// MODE 1: epilogue -> float C row-major [M][N].
template <int MODE>
__global__ __launch_bounds__(512, 1) void gemm256(const __hip_bfloat16* __restrict__ A,
                                                  const __hip_bfloat16* __restrict__ Bw,
                                                  __hip_bfloat16* __restrict__ Cbf,
                                                  __hip_bfloat16* __restrict__ Vt,
                                                  float* __restrict__ Cf,
                                                  const float* __restrict__ fc,
                                                  const float* __restrict__ fs,
                                                  const int* __restrict__ posp,
                                                  int M, int N, int K) {
  __shared__ __hip_bfloat16 As[2][2][128 * 64];  // [buf][half][row*64+col]  64KB
  __shared__ __hip_bfloat16 Bs[2][2][128 * 64];  // 64KB
  const int tid = threadIdx.x;
  const int wid = tid >> 6, lane = tid & 63;
  const int l15 = lane & 15, l4 = lane >> 4;
  const int wm = wid >> 2, wn = wid & 3;  // 2 x 4 wave grid; wave owns 128x64

  const int nbn = N >> 8;
  const int nb = (M >> 8) * nbn;
  const int bid = blockIdx.x;
  const int swz = (bid & 7) * (nb >> 3) + (bid >> 3);  // XCD-contiguous (nb%8==0)
  const int bm = swz / nbn, bn = swz % nbn;

  const int NT = K >> 6;  // K-tiles of 64

#define STAGE_HALF(Q, BUF, K0G)                                                   \
  {                                                                               \
    if ((Q) < 2) {                                                                \
      const long rowb = (long)bm * 256 + (Q) * 128;                               \
      _Pragma("unroll") for (int i = 0; i < 2; i++) {                             \
        int c = i * 512 + tid, rr = c >> 3, jj = (c & 7) ^ (rr & 7);              \
        gl_lds16(A + (rowb + rr) * (long)K + (K0G) + jj * 8,                      \
                 &As[BUF][(Q)][0] + c * 8);                                       \
      }                                                                           \
    } else {                                                                      \
      const long rowb = (long)bn * 256 + ((Q) - 2) * 128;                         \
      _Pragma("unroll") for (int i = 0; i < 2; i++) {                             \
        int c = i * 512 + tid, rr = c >> 3, jj = (c & 7) ^ (rr & 7);              \
        gl_lds16(Bw + (rowb + rr) * (long)K + (K0G) + jj * 8,                     \
                 &Bs[BUF][(Q) - 2][0] + c * 8);                                   \
      }                                                                           \
    }                                                                             \
  }

  f32x4 acc[8][4] = {};

  // prologue: tiles 0 and 1 fully staged
#pragma unroll
  for (int q = 0; q < 4; ++q) STAGE_HALF(q, 0, 0);
#pragma unroll
  for (int q = 0; q < 4; ++q) STAGE_HALF(q, 1, 64);
  __syncthreads();  // vmcnt(0)+lgkm(0)+barrier

  for (int T = 0; T < NT; ++T) {
    const int cur = T & 1;
    const int nxt = cur ^ 1;
    const bool do_stage = (T >= 1) && (T + 1 < NT);
    const int k0n = (T + 1) << 6;

#pragma unroll
    for (int k2 = 0; k2 < 2; ++k2) {
      bf16x8 af[8], bg[4];
#pragma unroll
      for (int ni = 0; ni < 4; ni++) {
        int r = (wn & 1) * 64 + ni * 16 + l15;
        int j = (k2 * 4 + l4) ^ (r & 7);
        bg[ni] = *(const bf16x8*)(&Bs[cur][wn >> 1][0] + r * 64 + j * 8);
      }
#pragma unroll
      for (int mi = 0; mi < 8; mi++) {
        int r = mi * 16 + l15;
        int j = (k2 * 4 + l4) ^ (r & 7);
        af[mi] = *(const bf16x8*)(&As[cur][wm][0] + r * 64 + j * 8);
      }
      if (do_stage) {
        if (k2 == 0) { STAGE_HALF(0, nxt, k0n); STAGE_HALF(1, nxt, k0n); }
        else         { STAGE_HALF(2, nxt, k0n); STAGE_HALF(3, nxt, k0n); }
      }
      // no barrier, no setprio: scheduler free to interleave all waves' work
#pragma unroll
      for (int mi = 0; mi < 8; mi++)
#pragma unroll
        for (int ni = 0; ni < 4; ni++)
          acc[mi][ni] = __builtin_amdgcn_mfma_f32_16x16x32_bf16(af[mi], bg[ni],
                                                                acc[mi][ni], 0, 0, 0);
    }
    // single essential sync point per tile
    asm volatile("s_waitcnt vmcnt(0)" ::: "memory");
    __builtin_amdgcn_s_barrier();
    asm volatile("" ::: "memory");
  }
#undef STAGE_HALF

  // ---- epilogue ----
  if (MODE == 0) {
    if (bn * 256 < 4096) {
      const int pos = *posp;
#pragma unroll
      for (int mi = 0; mi < 8; mi++)
#pragma unroll
        for (int ni = 0; ni < 4; ni++) {
          int n = bn * 256 + wn * 64 + ni * 16 + l15;
          int hd = n & 127;
          int ip = hd >> 1;
          bool odd = hd & 1;
#pragma unroll
          for (int r = 0; r < 4; r++) {
            float v = acc[mi][ni][r];
            float p = __shfl_xor(v, 1, 64);
            int m = bm * 256 + wm * 128 + mi * 16 + l4 * 4 + r;
            int s = m & (SS - 1);
            float cv = fc[(long)(pos + s) * 64 + ip];
            float sv = fs[(long)(pos + s) * 64 + ip];
            float out = odd ? (p * sv + v * cv) : (v * cv - p * sv);
            Cbf[(long)m * 4096 + n] = __float2bfloat16(out);
          }
        }
    } else {
#pragma unroll
      for (int mi = 0; mi < 8; mi++)
#pragma unroll
        for (int ni = 0; ni < 4; ni++) {
          int e = bn * 256 + wn * 64 + ni * 16 + l15 - 4096;
          int hh = e >> 7, hd = e & 127;
          int m0 = bm * 256 + wm * 128 + mi * 16 + l4 * 4;
          int b = m0 >> 11, s0 = m0 & (SS - 1);
          u16x4 pk;
#pragma unroll
          for (int r = 0; r < 4; r++) pk[r] = f2bf(acc[mi][ni][r]);
          *(u16x4*)(Vt + (((long)(b * HH + hh) * 128 + hd) * SS + s0)) = pk;
        }
    }
  } else {
#pragma unroll
    for (int mi = 0; mi < 8; mi++)
#pragma unroll
      for (int ni = 0; ni < 4; ni++) {
        int n = bn * 256 + wn * 64 + ni * 16 + l15;
#pragma unroll
        for (int r = 0; r < 4; r++) {
          int m = bm * 256 + wm * 128 + mi * 16 + l4 * 4 + r;
          Cf[(long)m * N + n] = acc[mi][ni][r];
        }
      }
  }
}

// ---------------- causal flash attention (round-14, unchanged; keeps setprio) ----
__global__ __launch_bounds__(256, 2) void attn_k(const __hip_bfloat16* __restrict__ qk,
                                                 const __hip_bfloat16* __restrict__ vt,
                                                 __hip_bfloat16* __restrict__ aout,
                                                 const int* __restrict__ posp) {
  __shared__ __hip_bfloat16 Ks[64 * 128];
  __shared__ __hip_bfloat16 Vs[128 * 64];
  __shared__ __hip_bfloat16 Ps[4][16 * 64];
  const int pos = *posp;
  const int orig = blockIdx.x;
  const int swz = (orig & 7) * 128 + (orig >> 3);
  const int qp = swz & 15, bh = swz >> 4;
  const int b = bh >> 4, h = bh & 15;
  const int tid = threadIdx.x;
  const int wave = tid >> 6, lane = tid & 63;
  const int l15 = lane & 15, l4 = lane >> 4;

  const long kbase = ((long)b * SS) * 4096 + 2048 + h * 128;
  const long vbase = ((long)bh * 128) * SS;
  const float sc2 = 0.08838834764831845f * 1.4426950408889634f;

  const int s_kr[4] = {(0 * 256 + tid) >> 4, (1 * 256 + tid) >> 4, (2 * 256 + tid) >> 4, (3 * 256 + tid) >> 4};
  const int s_kc = tid & 15;
  const int s_hd[4] = {(0 * 256 + tid) >> 3, (1 * 256 + tid) >> 3, (2 * 256 + tid) >> 3, (3 * 256 + tid) >> 3};
  const int s_vc = tid & 7;

  bf16x8 kreg[4], vreg[4];

#define LOADKV(T)                                                                             \
  {                                                                                           \
    const int kv0_ = (T) * 64;                                                                \
    _Pragma("unroll") for (int i = 0; i < 4; i++) {                                           \
      kreg[i] = *(const bf16x8*)(qk + kbase + (long)(kv0_ + s_kr[i]) * 4096 + s_kc * 8);      \
      vreg[i] = *(const bf16x8*)(vt + vbase + (long)s_hd[i] * SS + kv0_ + s_vc * 8);          \
    }                                                                                         \
  }

#define STAGE()                                                                               \
  {                                                                                           \
    _Pragma("unroll") for (int i = 0; i < 4; i++) {                                           \
      *(bf16x8*)(Ks + ((s_kr[i] * 128 + s_kc * 8) ^ ((s_kr[i] & 7) << 3))) = kreg[i];         \
      *(bf16x8*)(Vs + ((s_hd[i] * 64 + s_vc * 8) ^ ((s_hd[i] & 7) << 3))) = vreg[i];          \
    }                                                                                         \
  }

  for (int half = 0; half < 2; ++half) {
    const int qb = half ? (31 - qp) : qp;
    const int qwb = qb * 64 + wave * 16;

    bf16x8 qf[4];
#pragma unroll
    for (int kk = 0; kk < 4; kk++) {
      long row = (long)b * SS + qwb + l15;
      qf[kk] = *(const bf16x8*)(qk + row * 4096 + h * 128 + kk * 32 + l4 * 8);
    }

    f32x4 accO[8] = {};
    float mrun[4], lrun[4];
#pragma unroll
    for (int r = 0; r < 4; r++) { mrun[r] = MINIT; lrun[r] = 0.f; }

    int ntiles = (pos + qb * 64 + 63) / 64 + 1;
    if (ntiles > SS / 64) ntiles = SS / 64;
#define TT(t) (half ? (ntiles - 1 - (t)) : (t))

    LOADKV(TT(0));
    __syncthreads();
    STAGE();

    for (int t = 0; t < ntiles; ++t) {
      const int kv0 = TT(t) * 64;
      __syncthreads();
      if (t + 1 < ntiles) LOADKV(TT(t + 1));

      f32x4 sfr[4] = {};
      __builtin_amdgcn_s_setprio(1);
#pragma unroll
      for (int ni = 0; ni < 4; ni++) {
        const int key = ni * 16 + l15;
        const int sw = (key & 7) << 3;
#pragma unroll
        for (int kk = 0; kk < 4; kk++) {
          bf16x8 kf = *(const bf16x8*)(Ks + ((key * 128 + kk * 32 + l4 * 8) ^ sw));
          sfr[ni] = __builtin_amdgcn_mfma_f32_16x16x32_bf16(qf[kk], kf, sfr[ni], 0, 0, 0);
        }
      }
      __builtin_amdgcn_s_setprio(0);

      const bool needmask = (kv0 + 63) > (pos + qb * 64);
#pragma unroll
      for (int ni = 0; ni < 4; ni++)
#pragma unroll
        for (int r = 0; r < 4; r++) {
          float v = sfr[ni][r] * sc2;
          if (needmask) {
            int key = kv0 + ni * 16 + l15;
            int q = qwb + l4 * 4 + r;
            if (key > pos + q) v = MASKV;
          }
          sfr[ni][r] = v;
        }

      {
        f32x4 mx = sfr[0];
#pragma unroll
        for (int ni = 1; ni < 4; ni++)
#pragma unroll
          for (int r = 0; r < 4; r++) mx[r] = fmaxf(mx[r], sfr[ni][r]);
#pragma unroll
        for (int d = 1; d < 16; d <<= 1)
#pragma unroll
          for (int r = 0; r < 4; r++) mx[r] = fmaxf(mx[r], __shfl_xor(mx[r], d, 64));

        float growth = mx[0] - mrun[0];
#pragma unroll
        for (int r = 1; r < 4; r++) growth = fmaxf(growth, mx[r] - mrun[r]);
        if (!__all(growth <= 11.0f)) {
          float scal[4];
#pragma unroll
          for (int r = 0; r < 4; r++) {
            float mn = fmaxf(mrun[r], mx[r]);
            scal[r] = exp2f(mrun[r] - mn);
            mrun[r] = mn;
            lrun[r] *= scal[r];   // scal uniform across 16-lane group: valid on partials
          }
#pragma unroll
          for (int ni = 0; ni < 8; ni++)
#pragma unroll
            for (int r = 0; r < 4; r++) accO[ni][r] *= scal[r];
        }

        // per-lane partial sum; cross-lane reduce deferred to epilogue
#pragma unroll
        for (int ni = 0; ni < 4; ni++)
#pragma unroll
          for (int r = 0; r < 4; r++) {
            float p = exp2f(sfr[ni][r] - mrun[r]);
            lrun[r] += p;
            int prow = l4 * 4 + r;
            Ps[wave][(prow * 64 + ni * 16 + l15) ^ ((prow & 7) << 3)] = __float2bfloat16(p);
          }
      }

      __builtin_amdgcn_s_setprio(1);
#pragma unroll
      for (int kk = 0; kk < 2; kk++) {
        int prow = l15;
        bf16x8 pf = *(const bf16x8*)(Ps[wave] + ((prow * 64 + kk * 32 + l4 * 8) ^ ((prow & 7) << 3)));
#pragma unroll
        for (int ni = 0; ni < 8; ni++) {
          int hd = ni * 16 + l15;
          bf16x8 vf = *(const bf16x8*)(Vs + ((hd * 64 + kk * 32 + l4 * 8) ^ ((hd & 7) << 3)));
          accO[ni] = __builtin_amdgcn_mfma_f32_16x16x32_bf16(pf, vf, accO[ni], 0, 0, 0);
        }
      }
      __builtin_amdgcn_s_setprio(0);

      __syncthreads();
      if (t + 1 < ntiles) STAGE();
    }
#undef TT

    // deferred cross-lane lrun reduce (once per q-half)
#pragma unroll
    for (int d = 1; d < 16; d <<= 1)
#pragma unroll
      for (int r = 0; r < 4; r++) lrun[r] += __shfl_xor(lrun[r], d, 64);

    __hip_bfloat16* E = Ks + wave * 2048;
    {
      float inv[4];
#pragma unroll
      for (int r = 0; r < 4; r++) inv[r] = 1.0f / lrun[r];
#pragma unroll
      for (int ni = 0; ni < 8; ni++)
#pragma unroll
        for (int r = 0; r < 4; r++) {
          int row = l4 * 4 + r;
          E[(row * 128 + ni * 16 + l15) ^ ((row & 7) << 3)] =
              __float2bfloat16(accO[ni][r] * inv[r]);
        }
    }
    const long gb = ((long)b * SS + qwb) * 2048 + h * 128;
#pragma unroll
    for (int j = 0; j < 4; j++) {
      int row = j * 4 + l4;
      int c8 = l15 * 8;
      bf16x8 v = *(const bf16x8*)(E + ((row * 128 + c8) ^ ((row & 7) << 3)));
      *(bf16x8*)(aout + gb + (long)row * 2048 + c8) = v;
    }
  }
#undef LOADKV
#undef STAGE
}

extern "C" void kernel_launch(void* const* d_in, const int* in_sizes, int n_in,
                              void* d_out, int out_size, void* d_ws, size_t ws_size,
                              hipStream_t stream) {
  (void)in_sizes; (void)n_in; (void)out_size; (void)ws_size;
  const float* h  = (const float*)d_in[0];
  const float* Wq = (const float*)d_in[1];
  const float* Wk = (const float*)d_in[2];
  const float* Wv = (const float*)d_in[3];
  const float* Wo = (const float*)d_in[4];
  const float* fc = (const float*)d_in[7];
  const float* fs = (const float*)d_in[8];
  const int* pos  = (const int*)d_in[9];
  float* out = (float*)d_out;

  char* ws = (char*)d_ws;
  __hip_bfloat16* hb    = (__hip_bfloat16*)(ws);                 // 33,554,432 B
  __hip_bfloat16* wqkv  = (__hip_bfloat16*)(ws + 33554432);      // 25,165,824 B
  __hip_bfloat16* wo_b  = (__hip_bfloat16*)(ws + 58720256);      //  8,388,608 B
  __hip_bfloat16* qkbuf = (__hip_bfloat16*)(ws + 67108864);      // 67,108,864 B
  __hip_bfloat16* vt    = (__hip_bfloat16*)(ws + 134217728);     // 33,554,432 B
  __hip_bfloat16* aout  = hb;  // alias: hb dead after GEMM1

  // fused fp32 -> bf16 (h + Wq + Wk + Wv + Wo), single launch
  convert_all<<<32768, 256, 0, stream>>>(h, Wq, Wk, Wv, Wo, hb, wqkv, wo_b);

  // QKV projection + fused RoPE: M=8192, N=6144, K=2048  (32x24=768 blocks)
  gemm256<0><<<768, 512, 0, stream>>>(hb, wqkv, qkbuf, vt, nullptr, fc, fs, pos,
                                      8192, 6144, 2048);

  // causal flash attention (balanced, two-stream L2-local, 1024 blocks x 256 threads)
  attn_k<<<1024, 256, 0, stream>>>(qkbuf, vt, aout, pos);

  // output projection: M=8192, N=2048, K=2048 -> fp32 d_out  (32x8=256 blocks)
  gemm256<1><<<256, 512, 0, stream>>>(aout, wo_b, nullptr, nullptr, out, nullptr,
                                      nullptr, nullptr, 8192, 2048, 2048);
}